// Round 5
// baseline (660.191 us; speedup 1.0000x reference)
//
#include <hip/hip_runtime.h>
#include <math.h>
#include <stdint.h>

typedef _Float16 half8 __attribute__((ext_vector_type(8)));
typedef _Float16 half4h __attribute__((ext_vector_type(4)));
typedef float f32x4 __attribute__((ext_vector_type(4)));

#define ACOLS 232   // halfs per padded row (cols -3..228)
#define AROWS 100   // 99 real rows (9 planes x 11 ih rows) + 1 zero row

// ---------------- Kernel P: pad + fp16-ify rgb -> pim[b][tp(92)][c][ihp(227)][232] ----------
__global__ __launch_bounds__(256) void pad_kernel(const float* __restrict__ rgb,
                                                  _Float16* __restrict__ pim)
{
    int idx = blockIdx.x * 256 + threadIdx.x;       // one half8 segment each
    if (idx >= 250608 * 29) return;                  // rows = 4*92*3*227
    int row = idx / 29, seg = idx - row * 29;
    int ihp = row % 227; int pr = row / 227;         // pr = (b*92+tp)*3+c
    int c = pr % 3; int btp = pr / 3;
    int tp = btp % 92; int b = btp / 92;
    int t = tp - 1, ih = ihp - 3;
    float v[8];
    #pragma unroll
    for (int j = 0; j < 8; ++j) v[j] = 0.f;
    if ((unsigned)t < 90u && (unsigned)ih < 224u) {
        const float* src = rgb + (((size_t)(b * 90 + t) * 3 + c) * 224 + ih) * 224;
        if (seg >= 1 && seg <= 27) {
            __builtin_memcpy(v, src + seg * 8 - 3, 32);    // 4B-aligned 32B
        } else if (seg == 0) {                              // cols -3..4
            #pragma unroll
            for (int j = 3; j < 8; ++j) v[j] = src[j - 3];
        } else {                                            // seg 28: cols 221..228
            #pragma unroll
            for (int j = 0; j < 3; ++j) v[j] = src[221 + j];
        }
    }
    half8 hv;
    #pragma unroll
    for (int j = 0; j < 8; ++j) hv[j] = (_Float16)v[j];
    *(half8*)(pim + (size_t)row * ACOLS + seg * 8) = hv;
}

// ---------------- Kernel 0: weights -> wBh[rowlog(72)][co(64)][kw(8)] fp16 ----------------
__global__ void wprep_kernel(const float* __restrict__ conv_w, _Float16* __restrict__ wBh)
{
    int idx = blockIdx.x * 256 + threadIdx.x;   // 36864
    if (idx >= 36864) return;
    int rowlog = idx >> 9, rem = idx & 511, co = rem >> 3, kw = rem & 7;
    int p = rowlog >> 3, khs = rowlog & 7;
    int c = p / 3, kt = p - c * 3;
    float v = 0.f;
    if (khs < 7 && kw < 7)
        v = conv_w[(((size_t)(co * 3 + c) * 3 + kt) * 7 + khs) * 7 + kw];
    wBh[idx] = (_Float16)v;
}

// 8B-aligned 16-byte LDS load (two ds_read_b64)
static __device__ __forceinline__ half8 ld8(const _Float16* p) {
    half4h lo = *(const half4h*)p;
    half4h hi = *(const half4h*)(p + 4);
    return __builtin_shufflevector(lo, hi, 0, 1, 2, 3, 4, 5, 6, 7);
}

// Exact-accuracy GELU: Abramowitz-Stegun 7.1.26 erf (|err| <= 1.5e-7), branchless.
static __device__ __forceinline__ float gelu_exact(float v) {
    float z = __builtin_fabsf(v) * 0.70710678118654752f;
    float t = __builtin_amdgcn_rcpf(__builtin_fmaf(0.3275911f, z, 1.f));
    float p = __builtin_fmaf(1.061405429f, t, -1.453152027f);
    p = __builtin_fmaf(p, t, 1.421413741f);
    p = __builtin_fmaf(p, t, -0.284496736f);
    p = __builtin_fmaf(p, t, 0.254829592f);
    p *= t;
    float e = __expf(-z * z);
    float er = __builtin_fmaf(-p, e, 1.f);      // erf(|v|/sqrt2)
    float se = __builtin_copysignf(er, v);
    return 0.5f * v * (1.f + se);
}

typedef const __attribute__((address_space(1))) uint32_t gu32;
typedef __attribute__((address_space(3))) uint32_t lu32;

// ---------------- Kernel 1: conv3d (fp16 MFMA) + BN + GELU + pool-over-ow, 2 oh/block -----
// grid (28, 360), block 256 (4 waves). M=128 (2 oh x 64 ow-pad), N=64 co, K=576.
// Wave layout: wid -> (h = wid>>1, owt = wid&1); each wave owns 1 oh x 32 ow x ALL 64 co,
// so each A-fragment LDS read feeds 4 MFMAs (halves LDS read traffic vs co-split layout).
__global__ __launch_bounds__(256) void conv_mfma_kernel(
    const _Float16* __restrict__ pim, const _Float16* __restrict__ wBh,
    const float* __restrict__ conv_b, const float* __restrict__ bn_gamma,
    const float* __restrict__ bn_beta, const float* __restrict__ bn_mean,
    const float* __restrict__ bn_var, float* __restrict__ partial)
{
    __shared__ __align__(16) char smem[AROWS * ACOLS * 2];   // 46,400 B
    _Float16* s_a = (_Float16*)smem;
    float*    s_r = (float*)smem;    // reused: [8 wq][2 h][64 co][3 bin] = 12 KB

    const int bx = blockIdx.x;      // oh = 2*bx + h
    const int bt = blockIdx.y;
    const int b = bt / 90, t = bt % 90;
    const int tid = threadIdx.x;
    const int lane = tid & 63;
    const int wid = __builtin_amdgcn_readfirstlane(tid >> 6);

    // ---- staging via global_load_lds DMA: 9 contiguous planes x 5104 B each ----
    for (int cid = wid; cid < 45; cid += 4) {
        int p = cid / 5, j = cid - p * 5;            // wave-uniform
        int c = p / 3, kt = p - c * 3;
        const char* gsrc = (const char*)(pim +
            ((size_t)((b * 92 + t + kt) * 3 + c) * 227 + 8 * bx) * ACOLS)
            + j * 1024 + lane * 16;
        char* ldst = smem + p * 5104 + j * 1024;     // uniform; HW adds lane*16
        if (j < 4 || lane < 63)
            __builtin_amdgcn_global_load_lds((gu32*)gsrc, (lu32*)ldst, 16, 0, 0);
    }
    if (tid < 29) {                                   // zero row r=99
        half8 z = {};
        *(half8*)(s_a + 99 * ACOLS + tid * 8) = z;
    }
    __syncthreads();

    const int h   = wid >> 1;       // oh sub-row owned by this wave
    const int owt = wid & 1;        // ow half owned by this wave
    const int l15 = lane & 15, q = lane >> 4;

    f32x4 acc[2][4] = {};           // [i(m-sub)][n(co-tile)]
    int owA = owt * 32 + l15;                   // 0-15 / 32-47
    int owB = owA + 16;  if (owB > 55) owB = 55; // 16-31 / 48-63(clamped)
    // per-lane LDS bases (h and q folded in); per-kk offsets become ds_read immediates
    const _Float16* baseA = s_a + (q + 4 * h) * ACOLS + 4 * owA;
    const _Float16* baseB = s_a + (q + 4 * h) * ACOLS + 4 * owB;
    const _Float16* bp = wBh + (size_t)q * 512 + l15 * 8;   // + n*128 halfs per co-tile

    // prefetch BN/bias params so their latency hides under the MFMA loop
    float vg[4], vv[4], vb[4], vm[4], vc[4];
    #pragma unroll
    for (int n = 0; n < 4; ++n) {
        int co = n * 16 + l15;
        vg[n] = bn_gamma[co]; vv[n] = bn_var[co]; vb[n] = bn_beta[co];
        vm[n] = bn_mean[co];  vc[n] = conv_b[co];
    }

    // row(kk,q) = 4kk + 3*(kk>>1) + q  (q folded into baseA/baseB)
    // rowlog(kk,q) = 4kk + q -> wBh offset (4kk+q)*512 = kk*2048 + q*512
    #pragma unroll
    for (int kk = 0; kk < 18; ++kk) {
        const int ro = (4 * kk + 3 * (kk >> 1)) * ACOLS;       // constexpr after unroll
        half8 b0 = *(const half8*)(bp + (size_t)kk * 2048);
        half8 b1 = *(const half8*)(bp + (size_t)kk * 2048 + 128);
        half8 b2 = *(const half8*)(bp + (size_t)kk * 2048 + 256);
        half8 b3 = *(const half8*)(bp + (size_t)kk * 2048 + 384);
        half8 a0 = ld8(baseA + ro);
        half8 a1 = ld8(baseB + ro);

        acc[0][0] = __builtin_amdgcn_mfma_f32_16x16x32_f16(a0, b0, acc[0][0], 0, 0, 0);
        acc[0][1] = __builtin_amdgcn_mfma_f32_16x16x32_f16(a0, b1, acc[0][1], 0, 0, 0);
        acc[0][2] = __builtin_amdgcn_mfma_f32_16x16x32_f16(a0, b2, acc[0][2], 0, 0, 0);
        acc[0][3] = __builtin_amdgcn_mfma_f32_16x16x32_f16(a0, b3, acc[0][3], 0, 0, 0);
        acc[1][0] = __builtin_amdgcn_mfma_f32_16x16x32_f16(a1, b0, acc[1][0], 0, 0, 0);
        acc[1][1] = __builtin_amdgcn_mfma_f32_16x16x32_f16(a1, b1, acc[1][1], 0, 0, 0);
        acc[1][2] = __builtin_amdgcn_mfma_f32_16x16x32_f16(a1, b2, acc[1][2], 0, 0, 0);
        acc[1][3] = __builtin_amdgcn_mfma_f32_16x16x32_f16(a1, b3, acc[1][3], 0, 0, 0);
    }
    __syncthreads();   // done with s_a; reuse as s_r

    // ---- epilogue: bias+BN+exact GELU (fast erf), in-register 3-bin ow pooling ----
    #pragma unroll
    for (int n = 0; n < 4; ++n) {
        float inv = vg[n] / sqrtf(vv[n] + 1e-5f);
        float sh  = vb[n] - vm[n] * inv;
        float cb  = vc[n];
        float s0 = 0.f, s1 = 0.f, s2 = 0.f;
        #pragma unroll
        for (int i = 0; i < 2; ++i) {
            #pragma unroll
            for (int reg = 0; reg < 4; ++reg) {
                int m = owt * 32 + i * 16 + q * 4 + reg;   // ow
                float v = (acc[i][n][reg] + cb) * inv + sh;
                float g = gelu_exact(v);
                s0 += (m < 18) ? g : 0.f;
                s1 += (m >= 18 && m < 37) ? g : 0.f;
                s2 += (m >= 37 && m < 56) ? g : 0.f;
            }
        }
        int co = n * 16 + l15;
        float* dst = s_r + (((owt * 4 + q) * 2 + h) * 64 + co) * 3;
        dst[0] = s0; dst[1] = s1; dst[2] = s2;
    }
    __syncthreads();

    if (tid < 192) {    // 64 co x 3 bins; reduce 8 (owt,q) partials, both oh rows
        int co = tid / 3, j = tid % 3;
        #pragma unroll
        for (int hh = 0; hh < 2; ++hh) {
            float s = 0.f;
            #pragma unroll
            for (int wq = 0; wq < 8; ++wq)
                s += s_r[((wq * 2 + hh) * 64 + co) * 3 + j];
            partial[((size_t)(bt * 56 + 2 * bx + hh) * 64 + co) * 3 + j] = s;
        }
    }
}

// ---------------- Kernel 2: fused pool-over-oh + proj + in_proj -> xm_raw [bt][512] --------
__global__ __launch_bounds__(256) void ppi_kernel(
    const float* __restrict__ partial, const float* __restrict__ proj_w,
    const float* __restrict__ proj_b, const float* __restrict__ m_in_w,
    float* __restrict__ xm_raw)
{
    __shared__ __align__(16) float s_part[10752];   // [oh 56][co 64][3]
    __shared__ __align__(16) float s_pool[576];
    __shared__ __align__(16) float s_xp[128];
    int bt = blockIdx.x, tid = threadIdx.x;

    const f32x4* src4 = (const f32x4*)(partial + (size_t)bt * 10752);
    f32x4* dst4 = (f32x4*)s_part;
    for (int i = tid; i < 2688; i += 256) dst4[i] = src4[i];
    __syncthreads();

    for (int f = tid; f < 576; f += 256) {
        int co = f / 9, r = f % 9, i = r / 3, j = r % 3;
        const int sh[3] = {0, 18, 37}, eh[3] = {18, 37, 56};
        const float cnt[3] = {18.f, 19.f, 19.f};
        float s = 0.f;
        for (int oh = sh[i]; oh < eh[i]; ++oh)
            s += s_part[oh * 192 + co * 3 + j];
        s_pool[f] = s / (cnt[i] * cnt[j]);
    }
    __syncthreads();
    if (tid < 128) {
        const f32x4* w = (const f32x4*)(proj_w + (size_t)tid * 576);
        const f32x4* x4 = (const f32x4*)s_pool;
        f32x4 a = {};
        #pragma unroll 4
        for (int f = 0; f < 144; ++f) a += w[f] * x4[f];
        s_xp[tid] = proj_b[tid] + a.x + a.y + a.z + a.w;
    }
    __syncthreads();
    for (int o = tid; o < 512; o += 256) {
        const f32x4* w = (const f32x4*)(m_in_w + (size_t)o * 128);
        const f32x4* x4 = (const f32x4*)s_xp;
        f32x4 a = {};
        #pragma unroll 4
        for (int f = 0; f < 32; ++f) a += w[f] * x4[f];
        xm_raw[(size_t)bt * 512 + o] = a.x + a.y + a.z + a.w;
    }
}

// ---------------- Kernel 3: fused dwconv+silu -> xc, xdbl, delta ----------------
__global__ __launch_bounds__(256) void dxd_kernel(
    const float* __restrict__ xm_raw, const float* __restrict__ m_conv_w,
    const float* __restrict__ m_conv_b, const float* __restrict__ m_x_w,
    const float* __restrict__ m_dt_w, const float* __restrict__ m_dt_b,
    float* __restrict__ xc, float* __restrict__ xdbl, float* __restrict__ delta)
{
    __shared__ __align__(16) float s_xc[256];
    __shared__ float s_xd[40];
    int bt = blockIdx.x, d = threadIdx.x;
    int b = bt / 90, l = bt % 90;
    float s = m_conv_b[d];
    #pragma unroll
    for (int k = 0; k < 4; ++k) {
        int lk = l - 3 + k;
        if (lk >= 0) s += xm_raw[(size_t)(b * 90 + lk) * 512 + d] * m_conv_w[d * 4 + k];
    }
    float xcv = s / (1.f + expf(-s));
    s_xc[d] = xcv;
    xc[(size_t)bt * 256 + d] = xcv;
    __syncthreads();
    if (d < 40) {
        const f32x4* w = (const f32x4*)(m_x_w + (size_t)d * 256);
        const f32x4* x4 = (const f32x4*)s_xc;
        f32x4 a = {};
        #pragma unroll 4
        for (int f = 0; f < 64; ++f) a += w[f] * x4[f];
        float v = a.x + a.y + a.z + a.w;
        s_xd[d] = v;
        xdbl[(size_t)bt * 40 + d] = v;
    }
    __syncthreads();
    float t2 = m_dt_b[d];
    #pragma unroll
    for (int r = 0; r < 8; ++r) t2 += s_xd[r] * m_dt_w[d * 8 + r];
    delta[(size_t)bt * 256 + d] = (t2 > 20.f) ? t2 : log1pf(expf(t2));
}

// ---------------- Kernel 4: selective scan (8 blocks x 128 thr) ----------------
__global__ __launch_bounds__(128) void scan_kernel(
    const float* __restrict__ xc, const float* __restrict__ xdbl,
    const float* __restrict__ delta, const float* __restrict__ m_A_log,
    const float* __restrict__ m_D, const float* __restrict__ xm_raw,
    float* __restrict__ y)
{
    int b = blockIdx.x >> 1;
    int d = (blockIdx.x & 1) * 128 + threadIdx.x;
    float A[16], h[16];
    #pragma unroll
    for (int n = 0; n < 16; ++n) { A[n] = -expf(m_A_log[d * 16 + n]); h[n] = 0.f; }
    float Dd = m_D[d];
    size_t base = (size_t)b * 90;
    float dl = delta[base * 256 + d];
    float x  = xc[base * 256 + d];
    float r  = xm_raw[base * 512 + 256 + d];
    for (int l = 0; l < 90; ++l) {
        size_t bt = base + l;
        float dln = 0.f, xn = 0.f, rn = 0.f;
        if (l < 89) {
            dln = delta[(bt + 1) * 256 + d];
            xn  = xc[(bt + 1) * 256 + d];
            rn  = xm_raw[(bt + 1) * 512 + 256 + d];
        }
        const float* Bc = xdbl + bt * 40 + 8;
        float yl = 0.f;
        #pragma unroll
        for (int n = 0; n < 16; ++n) {
            float dA = expf(dl * A[n]);
            h[n] = dA * h[n] + dl * Bc[n] * x;
            yl += h[n] * Bc[16 + n];
        }
        yl += x * Dd;
        float sr = r / (1.f + expf(-r));
        y[bt * 256 + d] = yl * sr;
        dl = dln; x = xn; r = rn;
    }
}

// ---------------- Kernel 5: y @ out_w.T -> out [bt][128] ----------------
__global__ __launch_bounds__(128) void outproj_kernel(
    const float* __restrict__ y, const float* __restrict__ m_out_w,
    float* __restrict__ out)
{
    __shared__ __align__(16) float s_y[256];
    int bt = blockIdx.x, tid = threadIdx.x;
    for (int i = tid; i < 256; i += 128) s_y[i] = y[(size_t)bt * 256 + i];
    __syncthreads();
    const f32x4* w = (const f32x4*)(m_out_w + (size_t)tid * 256);
    const f32x4* x4 = (const f32x4*)s_y;
    f32x4 a = {};
    #pragma unroll 4
    for (int f = 0; f < 64; ++f) a += w[f] * x4[f];
    out[(size_t)bt * 128 + tid] = a.x + a.y + a.z + a.w;
}

extern "C" void kernel_launch(void* const* d_in, const int* in_sizes, int n_in,
                              void* d_out, int out_size, void* d_ws, size_t ws_size,
                              hipStream_t stream) {
    const float* rgb      = (const float*)d_in[0];
    const float* conv_w   = (const float*)d_in[1];
    const float* conv_b   = (const float*)d_in[2];
    const float* bn_gamma = (const float*)d_in[3];
    const float* bn_beta  = (const float*)d_in[4];
    const float* bn_mean  = (const float*)d_in[5];
    const float* bn_var   = (const float*)d_in[6];
    const float* proj_w   = (const float*)d_in[7];
    const float* proj_b   = (const float*)d_in[8];
    const float* m_in_w   = (const float*)d_in[9];
    const float* m_conv_w = (const float*)d_in[10];
    const float* m_conv_b = (const float*)d_in[11];
    const float* m_x_w    = (const float*)d_in[12];
    const float* m_dt_w   = (const float*)d_in[13];
    const float* m_dt_b   = (const float*)d_in[14];
    const float* m_A_log  = (const float*)d_in[15];
    const float* m_D      = (const float*)d_in[16];
    const float* m_out_w  = (const float*)d_in[17];
    float* out = (float*)d_out;

    float* ws      = (float*)d_ws;
    float* partial = ws;                  // 3,870,720 floats
    float* xm_raw  = partial + 3870720;   // 184,320
    float* xc      = xm_raw + 184320;     // 92,160
    float* xdbl    = xc + 92160;          // 14,400
    float* delta   = xdbl + 14400;        // 92,160
    float* yb      = delta + 92160;       // 92,160
    _Float16* wBh  = (_Float16*)(yb + 92160);      // 36,864 halfs
    _Float16* pim  = (_Float16*)(yb + 92160 + 18432);  // 58,132,416 halfs (~116 MB)

    pad_kernel<<<28390, 256, 0, stream>>>(rgb, pim);
    wprep_kernel<<<144, 256, 0, stream>>>(conv_w, wBh);
    conv_mfma_kernel<<<dim3(28, 360), 256, 0, stream>>>(pim, wBh, conv_b, bn_gamma,
                                                        bn_beta, bn_mean, bn_var, partial);
    ppi_kernel<<<360, 256, 0, stream>>>(partial, proj_w, proj_b, m_in_w, xm_raw);
    dxd_kernel<<<360, 256, 0, stream>>>(xm_raw, m_conv_w, m_conv_b, m_x_w,
                                        m_dt_w, m_dt_b, xc, xdbl, delta);
    scan_kernel<<<8, 128, 0, stream>>>(xc, xdbl, delta, m_A_log, m_D, xm_raw, yb);
    outproj_kernel<<<360, 128, 0, stream>>>(yb, m_out_w, out);
}

// Round 6
// 641.901 us; speedup vs baseline: 1.0285x; 1.0285x over previous
//
#include <hip/hip_runtime.h>
#include <math.h>
#include <stdint.h>

typedef _Float16 half8 __attribute__((ext_vector_type(8)));
typedef _Float16 half4h __attribute__((ext_vector_type(4)));
typedef float f32x4 __attribute__((ext_vector_type(4)));

#define ACOLS 232   // halfs per padded row (cols -3..228)
#define AROWS 100   // 99 real rows (9 planes x 11 ih rows) + 1 zero row

// ---------------- Kernel P: pad + fp16-ify rgb -> pim[b][tp(92)][c][ihp(227)][232] ----------
__global__ __launch_bounds__(256) void pad_kernel(const float* __restrict__ rgb,
                                                  _Float16* __restrict__ pim)
{
    int idx = blockIdx.x * 256 + threadIdx.x;       // one half8 segment each
    if (idx >= 250608 * 29) return;                  // rows = 4*92*3*227
    int row = idx / 29, seg = idx - row * 29;
    int ihp = row % 227; int pr = row / 227;         // pr = (b*92+tp)*3+c
    int c = pr % 3; int btp = pr / 3;
    int tp = btp % 92; int b = btp / 92;
    int t = tp - 1, ih = ihp - 3;
    float v[8];
    #pragma unroll
    for (int j = 0; j < 8; ++j) v[j] = 0.f;
    if ((unsigned)t < 90u && (unsigned)ih < 224u) {
        const float* src = rgb + (((size_t)(b * 90 + t) * 3 + c) * 224 + ih) * 224;
        if (seg >= 1 && seg <= 27) {
            __builtin_memcpy(v, src + seg * 8 - 3, 32);    // 4B-aligned 32B
        } else if (seg == 0) {                              // cols -3..4
            #pragma unroll
            for (int j = 3; j < 8; ++j) v[j] = src[j - 3];
        } else {                                            // seg 28: cols 221..228
            #pragma unroll
            for (int j = 0; j < 3; ++j) v[j] = src[221 + j];
        }
    }
    half8 hv;
    #pragma unroll
    for (int j = 0; j < 8; ++j) hv[j] = (_Float16)v[j];
    *(half8*)(pim + (size_t)row * ACOLS + seg * 8) = hv;
}

// ---------------- Kernel 0: weights -> wBh[rowlog(72)][co(64)][kw(8)] fp16 ----------------
__global__ void wprep_kernel(const float* __restrict__ conv_w, _Float16* __restrict__ wBh)
{
    int idx = blockIdx.x * 256 + threadIdx.x;   // 36864
    if (idx >= 36864) return;
    int rowlog = idx >> 9, rem = idx & 511, co = rem >> 3, kw = rem & 7;
    int p = rowlog >> 3, khs = rowlog & 7;
    int c = p / 3, kt = p - c * 3;
    float v = 0.f;
    if (khs < 7 && kw < 7)
        v = conv_w[(((size_t)(co * 3 + c) * 3 + kt) * 7 + khs) * 7 + kw];
    wBh[idx] = (_Float16)v;
}

// 8B-aligned 16-byte LDS load (two ds_read_b64)
static __device__ __forceinline__ half8 ld8(const _Float16* p) {
    half4h lo = *(const half4h*)p;
    half4h hi = *(const half4h*)(p + 4);
    return __builtin_shufflevector(lo, hi, 0, 1, 2, 3, 4, 5, 6, 7);
}

// Exact-accuracy GELU: Abramowitz-Stegun 7.1.26 erf (|err| <= 1.5e-7), branchless.
static __device__ __forceinline__ float gelu_exact(float v) {
    float z = __builtin_fabsf(v) * 0.70710678118654752f;
    float t = __builtin_amdgcn_rcpf(__builtin_fmaf(0.3275911f, z, 1.f));
    float p = __builtin_fmaf(1.061405429f, t, -1.453152027f);
    p = __builtin_fmaf(p, t, 1.421413741f);
    p = __builtin_fmaf(p, t, -0.284496736f);
    p = __builtin_fmaf(p, t, 0.254829592f);
    p *= t;
    float e = __expf(-z * z);
    float er = __builtin_fmaf(-p, e, 1.f);      // erf(|v|/sqrt2)
    float se = __builtin_copysignf(er, v);
    return 0.5f * v * (1.f + se);
}

typedef const __attribute__((address_space(1))) uint32_t gu32;
typedef __attribute__((address_space(3))) uint32_t lu32;

// ---------------- Kernel 1: conv3d (fp16 MFMA) + BN + GELU + pool-over-ow, 2 oh/block -----
// grid (28, 360), block 256 (4 waves). M=128 (2 oh x 64 ow-pad), N=64 co, K=576.
// Round-3 wave layout (verified): wave -> (wm = ow-half, wn = co-half), 8 MFMA/kk/wave.
// NEW: 9-phase plane-pipelined staging with counted vmcnt + raw s_barrier (T3/T4):
//   prologue issues planes 0..2; phase p waits own-DMA count (planes<=p+1 landed),
//   barriers, issues plane p+3, computes kk=2p,2p+1. Never drains vmcnt to 0 mid-loop.
__global__ __launch_bounds__(256) void conv_mfma_kernel(
    const _Float16* __restrict__ pim, const _Float16* __restrict__ wBh,
    const float* __restrict__ conv_b, const float* __restrict__ bn_gamma,
    const float* __restrict__ bn_beta, const float* __restrict__ bn_mean,
    const float* __restrict__ bn_var, float* __restrict__ partial)
{
    __shared__ __align__(16) char smem[AROWS * ACOLS * 2];   // 46,400 B
    _Float16* s_a = (_Float16*)smem;
    float*    s_r = (float*)smem;    // reused: [8 wq][2 h][64 co][3 bin] = 12 KB

    const int bx = blockIdx.x;      // oh = 2*bx + h
    const int bt = blockIdx.y;
    const int b = bt / 90, t = bt % 90;
    const int tid = threadIdx.x;
    const int lane = tid & 63;
    const int wid = __builtin_amdgcn_readfirstlane(tid >> 6);

    // plane p (= c*3+kt) DMA: 11 rows x 464 B = 5104 B contiguous in global AND LDS.
    // waves 0..2 issue one 1024B chunk; wave 3 issues 1024B + 1008B tail. c_w = {1,1,1,2}.
    auto stage = [&](int p) {
        int c_ = p / 3, kt_ = p - c_ * 3;
        const char* gp = (const char*)(pim +
            ((size_t)((b * 92 + t + kt_) * 3 + c_) * 227 + 8 * bx) * ACOLS);
        char* lp = smem + p * 5104;
        if (wid < 3) {
            __builtin_amdgcn_global_load_lds((gu32*)(gp + wid * 1024 + lane * 16),
                                             (lu32*)(lp + wid * 1024), 16, 0, 0);
        } else {
            __builtin_amdgcn_global_load_lds((gu32*)(gp + 3072 + lane * 16),
                                             (lu32*)(lp + 3072), 16, 0, 0);
            if (lane < 63)
                __builtin_amdgcn_global_load_lds((gu32*)(gp + 4096 + lane * 16),
                                                 (lu32*)(lp + 4096), 16, 0, 0);
        }
    };

    stage(0); stage(1); stage(2);
    if (tid < 29) {                                   // zero row r=99 (kh=7 pad, x0 weight)
        half8 z = {};
        *(half8*)(s_a + 99 * ACOLS + tid * 8) = z;
    }
    asm volatile("s_waitcnt lgkmcnt(0)" ::: "memory");   // zero-row write drained

    const int wn = wid & 1, wm = wid >> 1;
    const int l15 = lane & 15, q = lane >> 4;

    f32x4 acc[2][2][2] = {};                 // [h][i(m-sub)][n(co-sub)]
    int owA = wm * 32 + l15;  if (owA > 55) owA = 55;
    int owB = owA + 16;       if (owB > 55) owB = 55;
    const int co0 = wn * 32 + l15;
    const int co1 = co0 + 16;
    const _Float16* baseA = s_a + q * ACOLS + 4 * owA;
    const _Float16* baseB = s_a + q * ACOLS + 4 * owB;
    const _Float16* bp0 = wBh + (size_t)q * 512 + co0 * 8;
    const _Float16* bp1 = bp0 + 128;                     // co1 = co0+16

// one K-step: row(kk,q) = 4kk + 3*(kk>>1) + q (q folded into bases); B at (4kk+q)*512
#define KK(kkc) do { \
    const int ro = (4 * (kkc) + 3 * ((kkc) >> 1)) * ACOLS; \
    half8 b0 = *(const half8*)(bp0 + (size_t)(kkc) * 2048); \
    half8 b1 = *(const half8*)(bp1 + (size_t)(kkc) * 2048); \
    half8 a00 = ld8(baseA + ro); \
    half8 a01 = ld8(baseB + ro); \
    half8 a10 = ld8(baseA + ro + 4 * ACOLS); \
    half8 a11 = ld8(baseB + ro + 4 * ACOLS); \
    acc[0][0][0] = __builtin_amdgcn_mfma_f32_16x16x32_f16(a00, b0, acc[0][0][0], 0, 0, 0); \
    acc[0][0][1] = __builtin_amdgcn_mfma_f32_16x16x32_f16(a00, b1, acc[0][0][1], 0, 0, 0); \
    acc[0][1][0] = __builtin_amdgcn_mfma_f32_16x16x32_f16(a01, b0, acc[0][1][0], 0, 0, 0); \
    acc[0][1][1] = __builtin_amdgcn_mfma_f32_16x16x32_f16(a01, b1, acc[0][1][1], 0, 0, 0); \
    acc[1][0][0] = __builtin_amdgcn_mfma_f32_16x16x32_f16(a10, b0, acc[1][0][0], 0, 0, 0); \
    acc[1][0][1] = __builtin_amdgcn_mfma_f32_16x16x32_f16(a10, b1, acc[1][0][1], 0, 0, 0); \
    acc[1][1][0] = __builtin_amdgcn_mfma_f32_16x16x32_f16(a11, b0, acc[1][1][0], 0, 0, 0); \
    acc[1][1][1] = __builtin_amdgcn_mfma_f32_16x16x32_f16(a11, b1, acc[1][1][1], 0, 0, 0); \
} while (0)

// counted wait: own outstanding DMA chunks (wave 3 issues 2/plane, others 1)
#define WAITV(n1, n3) do { \
    if (wid == 3) asm volatile("s_waitcnt vmcnt(" #n3 ")" ::: "memory"); \
    else          asm volatile("s_waitcnt vmcnt(" #n1 ")" ::: "memory"); \
} while (0)

// phase p: planes <= p+1 landed; publish via raw barrier; prefetch p+3; compute plane p
#define PHASE(p, W) do { \
    W; \
    __builtin_amdgcn_s_barrier(); \
    if ((p) + 3 <= 8) stage((p) + 3); \
    __builtin_amdgcn_s_setprio(1); \
    KK(2 * (p)); \
    KK(2 * (p) + 1); \
    __builtin_amdgcn_s_setprio(0); \
} while (0)

    PHASE(0, WAITV(1, 2));
    PHASE(1, WAITV(1, 2));
    PHASE(2, WAITV(1, 2));
    PHASE(3, WAITV(1, 2));
    PHASE(4, WAITV(1, 2));
    PHASE(5, WAITV(1, 2));
    PHASE(6, WAITV(1, 2));
    PHASE(7, WAITV(0, 0));
    PHASE(8, WAITV(0, 0));

#undef PHASE
#undef WAITV
#undef KK

    // BN/bias params loaded after the K-loop (kept out of the counted vmcnt window)
    float vg0 = bn_gamma[co0], vg1 = bn_gamma[co1];
    float vv0 = bn_var[co0],   vv1 = bn_var[co1];
    float vb0 = bn_beta[co0],  vb1 = bn_beta[co1];
    float vm0 = bn_mean[co0],  vm1 = bn_mean[co1];
    float vc0 = conv_b[co0],   vc1 = conv_b[co1];

    __syncthreads();   // done with s_a; reuse as s_r (full drain OK here)

    // ---- epilogue: bias+BN+exact GELU (fast erf), in-register 3-bin ow pooling ----
    float inv[2], sh[2], cb[2];
    inv[0] = vg0 / sqrtf(vv0 + 1e-5f);
    sh[0]  = vb0 - vm0 * inv[0];
    cb[0]  = vc0;
    inv[1] = vg1 / sqrtf(vv1 + 1e-5f);
    sh[1]  = vb1 - vm1 * inv[1];
    cb[1]  = vc1;
    #pragma unroll
    for (int h = 0; h < 2; ++h) {
        #pragma unroll
        for (int n = 0; n < 2; ++n) {
            float s0 = 0.f, s1 = 0.f, s2 = 0.f;
            #pragma unroll
            for (int i = 0; i < 2; ++i) {
                #pragma unroll
                for (int reg = 0; reg < 4; ++reg) {
                    int m = wm * 32 + i * 16 + q * 4 + reg;   // ow
                    float v = (acc[h][i][n][reg] + cb[n]) * inv[n] + sh[n];
                    float g = gelu_exact(v);
                    s0 += (m < 18) ? g : 0.f;
                    s1 += (m >= 18 && m < 37) ? g : 0.f;
                    s2 += (m >= 37 && m < 56) ? g : 0.f;
                }
            }
            int co = n ? co1 : co0;
            float* dst = s_r + (((wm * 4 + q) * 2 + h) * 64 + co) * 3;
            dst[0] = s0; dst[1] = s1; dst[2] = s2;
        }
    }
    __syncthreads();

    if (tid < 192) {    // 64 co x 3 bins; reduce 8 wq partials, both oh rows
        int co = tid / 3, j = tid % 3;
        #pragma unroll
        for (int hh = 0; hh < 2; ++hh) {
            float s = 0.f;
            #pragma unroll
            for (int wq = 0; wq < 8; ++wq)
                s += s_r[((wq * 2 + hh) * 64 + co) * 3 + j];
            partial[((size_t)(bt * 56 + 2 * bx + hh) * 64 + co) * 3 + j] = s;
        }
    }
}

// ---------------- Kernel 2: fused pool-over-oh + proj + in_proj -> xm_raw [bt][512] --------
__global__ __launch_bounds__(256) void ppi_kernel(
    const float* __restrict__ partial, const float* __restrict__ proj_w,
    const float* __restrict__ proj_b, const float* __restrict__ m_in_w,
    float* __restrict__ xm_raw)
{
    __shared__ __align__(16) float s_part[10752];   // [oh 56][co 64][3]
    __shared__ __align__(16) float s_pool[576];
    __shared__ __align__(16) float s_xp[128];
    int bt = blockIdx.x, tid = threadIdx.x;

    const f32x4* src4 = (const f32x4*)(partial + (size_t)bt * 10752);
    f32x4* dst4 = (f32x4*)s_part;
    for (int i = tid; i < 2688; i += 256) dst4[i] = src4[i];
    __syncthreads();

    for (int f = tid; f < 576; f += 256) {
        int co = f / 9, r = f % 9, i = r / 3, j = r % 3;
        const int sh[3] = {0, 18, 37}, eh[3] = {18, 37, 56};
        const float cnt[3] = {18.f, 19.f, 19.f};
        float s = 0.f;
        for (int oh = sh[i]; oh < eh[i]; ++oh)
            s += s_part[oh * 192 + co * 3 + j];
        s_pool[f] = s / (cnt[i] * cnt[j]);
    }
    __syncthreads();
    if (tid < 128) {
        const f32x4* w = (const f32x4*)(proj_w + (size_t)tid * 576);
        const f32x4* x4 = (const f32x4*)s_pool;
        f32x4 a = {};
        #pragma unroll 4
        for (int f = 0; f < 144; ++f) a += w[f] * x4[f];
        s_xp[tid] = proj_b[tid] + a.x + a.y + a.z + a.w;
    }
    __syncthreads();
    for (int o = tid; o < 512; o += 256) {
        const f32x4* w = (const f32x4*)(m_in_w + (size_t)o * 128);
        const f32x4* x4 = (const f32x4*)s_xp;
        f32x4 a = {};
        #pragma unroll 4
        for (int f = 0; f < 32; ++f) a += w[f] * x4[f];
        xm_raw[(size_t)bt * 512 + o] = a.x + a.y + a.z + a.w;
    }
}

// ---------------- Kernel 3: fused dwconv+silu -> xc, xdbl, delta ----------------
__global__ __launch_bounds__(256) void dxd_kernel(
    const float* __restrict__ xm_raw, const float* __restrict__ m_conv_w,
    const float* __restrict__ m_conv_b, const float* __restrict__ m_x_w,
    const float* __restrict__ m_dt_w, const float* __restrict__ m_dt_b,
    float* __restrict__ xc, float* __restrict__ xdbl, float* __restrict__ delta)
{
    __shared__ __align__(16) float s_xc[256];
    __shared__ float s_xd[40];
    int bt = blockIdx.x, d = threadIdx.x;
    int b = bt / 90, l = bt % 90;
    float s = m_conv_b[d];
    #pragma unroll
    for (int k = 0; k < 4; ++k) {
        int lk = l - 3 + k;
        if (lk >= 0) s += xm_raw[(size_t)(b * 90 + lk) * 512 + d] * m_conv_w[d * 4 + k];
    }
    float xcv = s / (1.f + expf(-s));
    s_xc[d] = xcv;
    xc[(size_t)bt * 256 + d] = xcv;
    __syncthreads();
    if (d < 40) {
        const f32x4* w = (const f32x4*)(m_x_w + (size_t)d * 256);
        const f32x4* x4 = (const f32x4*)s_xc;
        f32x4 a = {};
        #pragma unroll 4
        for (int f = 0; f < 64; ++f) a += w[f] * x4[f];
        float v = a.x + a.y + a.z + a.w;
        s_xd[d] = v;
        xdbl[(size_t)bt * 40 + d] = v;
    }
    __syncthreads();
    float t2 = m_dt_b[d];
    #pragma unroll
    for (int r = 0; r < 8; ++r) t2 += s_xd[r] * m_dt_w[d * 8 + r];
    delta[(size_t)bt * 256 + d] = (t2 > 20.f) ? t2 : log1pf(expf(t2));
}

// ---------------- Kernel 4: selective scan (8 blocks x 128 thr) ----------------
__global__ __launch_bounds__(128) void scan_kernel(
    const float* __restrict__ xc, const float* __restrict__ xdbl,
    const float* __restrict__ delta, const float* __restrict__ m_A_log,
    const float* __restrict__ m_D, const float* __restrict__ xm_raw,
    float* __restrict__ y)
{
    int b = blockIdx.x >> 1;
    int d = (blockIdx.x & 1) * 128 + threadIdx.x;
    float A[16], h[16];
    #pragma unroll
    for (int n = 0; n < 16; ++n) { A[n] = -expf(m_A_log[d * 16 + n]); h[n] = 0.f; }
    float Dd = m_D[d];
    size_t base = (size_t)b * 90;
    float dl = delta[base * 256 + d];
    float x  = xc[base * 256 + d];
    float r  = xm_raw[base * 512 + 256 + d];
    for (int l = 0; l < 90; ++l) {
        size_t bt = base + l;
        float dln = 0.f, xn = 0.f, rn = 0.f;
        if (l < 89) {
            dln = delta[(bt + 1) * 256 + d];
            xn  = xc[(bt + 1) * 256 + d];
            rn  = xm_raw[(bt + 1) * 512 + 256 + d];
        }
        const float* Bc = xdbl + bt * 40 + 8;
        float yl = 0.f;
        #pragma unroll
        for (int n = 0; n < 16; ++n) {
            float dA = expf(dl * A[n]);
            h[n] = dA * h[n] + dl * Bc[n] * x;
            yl += h[n] * Bc[16 + n];
        }
        yl += x * Dd;
        float sr = r / (1.f + expf(-r));
        y[bt * 256 + d] = yl * sr;
        dl = dln; x = xn; r = rn;
    }
}

// ---------------- Kernel 5: y @ out_w.T -> out [bt][128] ----------------
__global__ __launch_bounds__(128) void outproj_kernel(
    const float* __restrict__ y, const float* __restrict__ m_out_w,
    float* __restrict__ out)
{
    __shared__ __align__(16) float s_y[256];
    int bt = blockIdx.x, tid = threadIdx.x;
    for (int i = tid; i < 256; i += 128) s_y[i] = y[(size_t)bt * 256 + i];
    __syncthreads();
    const f32x4* w = (const f32x4*)(m_out_w + (size_t)tid * 256);
    const f32x4* x4 = (const f32x4*)s_y;
    f32x4 a = {};
    #pragma unroll 4
    for (int f = 0; f < 64; ++f) a += w[f] * x4[f];
    out[(size_t)bt * 128 + tid] = a.x + a.y + a.z + a.w;
}

extern "C" void kernel_launch(void* const* d_in, const int* in_sizes, int n_in,
                              void* d_out, int out_size, void* d_ws, size_t ws_size,
                              hipStream_t stream) {
    const float* rgb      = (const float*)d_in[0];
    const float* conv_w   = (const float*)d_in[1];
    const float* conv_b   = (const float*)d_in[2];
    const float* bn_gamma = (const float*)d_in[3];
    const float* bn_beta  = (const float*)d_in[4];
    const float* bn_mean  = (const float*)d_in[5];
    const float* bn_var   = (const float*)d_in[6];
    const float* proj_w   = (const float*)d_in[7];
    const float* proj_b   = (const float*)d_in[8];
    const float* m_in_w   = (const float*)d_in[9];
    const float* m_conv_w = (const float*)d_in[10];
    const float* m_conv_b = (const float*)d_in[11];
    const float* m_x_w    = (const float*)d_in[12];
    const float* m_dt_w   = (const float*)d_in[13];
    const float* m_dt_b   = (const float*)d_in[14];
    const float* m_A_log  = (const float*)d_in[15];
    const float* m_D      = (const float*)d_in[16];
    const float* m_out_w  = (const float*)d_in[17];
    float* out = (float*)d_out;

    float* ws      = (float*)d_ws;
    float* partial = ws;                  // 3,870,720 floats
    float* xm_raw  = partial + 3870720;   // 184,320
    float* xc      = xm_raw + 184320;     // 92,160
    float* xdbl    = xc + 92160;          // 14,400
    float* delta   = xdbl + 14400;        // 92,160
    float* yb      = delta + 92160;       // 92,160
    _Float16* wBh  = (_Float16*)(yb + 92160);      // 36,864 halfs
    _Float16* pim  = (_Float16*)(yb + 92160 + 18432);  // 58,132,416 halfs (~116 MB)

    pad_kernel<<<28390, 256, 0, stream>>>(rgb, pim);
    wprep_kernel<<<144, 256, 0, stream>>>(conv_w, wBh);
    conv_mfma_kernel<<<dim3(28, 360), 256, 0, stream>>>(pim, wBh, conv_b, bn_gamma,
                                                        bn_beta, bn_mean, bn_var, partial);
    ppi_kernel<<<360, 256, 0, stream>>>(partial, proj_w, proj_b, m_in_w, xm_raw);
    dxd_kernel<<<360, 256, 0, stream>>>(xm_raw, m_conv_w, m_conv_b, m_x_w,
                                        m_dt_w, m_dt_b, xc, xdbl, delta);
    scan_kernel<<<8, 128, 0, stream>>>(xc, xdbl, delta, m_A_log, m_D, xm_raw, yb);
    outproj_kernel<<<360, 128, 0, stream>>>(yb, m_out_w, out);
}

// Round 7
// 631.253 us; speedup vs baseline: 1.0458x; 1.0169x over previous
//
#include <hip/hip_runtime.h>
#include <math.h>
#include <stdint.h>

typedef _Float16 half8 __attribute__((ext_vector_type(8)));
typedef _Float16 half4h __attribute__((ext_vector_type(4)));
typedef float f32x4 __attribute__((ext_vector_type(4)));

#define ACOLS 232   // halfs per padded row (cols -3..228)
#define AROWS 100   // 99 real rows (9 planes x 11 ih rows) + 1 zero row

// ---------------- Kernel P: pad + fp16-ify rgb -> pim[b][tp(92)][c][ihp(227)][232] ----------
__global__ __launch_bounds__(256) void pad_kernel(const float* __restrict__ rgb,
                                                  _Float16* __restrict__ pim)
{
    int idx = blockIdx.x * 256 + threadIdx.x;       // one half8 segment each
    if (idx >= 250608 * 29) return;                  // rows = 4*92*3*227
    int row = idx / 29, seg = idx - row * 29;
    int ihp = row % 227; int pr = row / 227;         // pr = (b*92+tp)*3+c
    int c = pr % 3; int btp = pr / 3;
    int tp = btp % 92; int b = btp / 92;
    int t = tp - 1, ih = ihp - 3;
    float v[8];
    #pragma unroll
    for (int j = 0; j < 8; ++j) v[j] = 0.f;
    if ((unsigned)t < 90u && (unsigned)ih < 224u) {
        const float* src = rgb + (((size_t)(b * 90 + t) * 3 + c) * 224 + ih) * 224;
        if (seg >= 1 && seg <= 27) {
            __builtin_memcpy(v, src + seg * 8 - 3, 32);    // 4B-aligned 32B
        } else if (seg == 0) {                              // cols -3..4
            #pragma unroll
            for (int j = 3; j < 8; ++j) v[j] = src[j - 3];
        } else {                                            // seg 28: cols 221..228
            #pragma unroll
            for (int j = 0; j < 3; ++j) v[j] = src[221 + j];
        }
    }
    half8 hv;
    #pragma unroll
    for (int j = 0; j < 8; ++j) hv[j] = (_Float16)v[j];
    *(half8*)(pim + (size_t)row * ACOLS + seg * 8) = hv;
}

// ---------------- Kernel 0: weights -> wBh[rowlog(72)][co(64)][kw(8)] fp16 ----------------
__global__ void wprep_kernel(const float* __restrict__ conv_w, _Float16* __restrict__ wBh)
{
    int idx = blockIdx.x * 256 + threadIdx.x;   // 36864
    if (idx >= 36864) return;
    int rowlog = idx >> 9, rem = idx & 511, co = rem >> 3, kw = rem & 7;
    int p = rowlog >> 3, khs = rowlog & 7;
    int c = p / 3, kt = p - c * 3;
    float v = 0.f;
    if (khs < 7 && kw < 7)
        v = conv_w[(((size_t)(co * 3 + c) * 3 + kt) * 7 + khs) * 7 + kw];
    wBh[idx] = (_Float16)v;
}

// 8B-aligned 16-byte LDS load (two ds_read_b64)
static __device__ __forceinline__ half8 ld8(const _Float16* p) {
    half4h lo = *(const half4h*)p;
    half4h hi = *(const half4h*)(p + 4);
    return __builtin_shufflevector(lo, hi, 0, 1, 2, 3, 4, 5, 6, 7);
}

// Exact-accuracy GELU: Abramowitz-Stegun 7.1.26 erf (|err| <= 1.5e-7), branchless.
static __device__ __forceinline__ float gelu_exact(float v) {
    float z = __builtin_fabsf(v) * 0.70710678118654752f;
    float t = __builtin_amdgcn_rcpf(__builtin_fmaf(0.3275911f, z, 1.f));
    float p = __builtin_fmaf(1.061405429f, t, -1.453152027f);
    p = __builtin_fmaf(p, t, 1.421413741f);
    p = __builtin_fmaf(p, t, -0.284496736f);
    p = __builtin_fmaf(p, t, 0.254829592f);
    p *= t;
    float e = __expf(-z * z);
    float er = __builtin_fmaf(-p, e, 1.f);      // erf(|v|/sqrt2)
    float se = __builtin_copysignf(er, v);
    return 0.5f * v * (1.f + se);
}

typedef const __attribute__((address_space(1))) uint32_t gu32;
typedef __attribute__((address_space(3))) uint32_t lu32;

// ---------------- Kernel 1: conv3d (fp16 MFMA) + BN + GELU + pool-over-ow, 2 oh/block -----
// grid (28, 360), block 256 (4 waves). M=128 (2 oh x 64 ow-pad), N=64 co, K=576.
// Round-3 wave layout (verified): wave -> (wm = ow-half, wn = co-half), 8 MFMA/kk/wave.
// Staging: ALL 9 planes issued fire-and-forget in the prologue (deep pipeline, round-3
// style); phase p waits a DECREASING counted vmcnt so planes <= p+1 are landed while the
// remaining planes stay in flight under compute (T3/T4). Never a mid-loop vmcnt(0) drain
// until phase 7 (by which time 7 phases of MFMA have covered the staging tail).
__global__ __launch_bounds__(256) void conv_mfma_kernel(
    const _Float16* __restrict__ pim, const _Float16* __restrict__ wBh,
    const float* __restrict__ conv_b, const float* __restrict__ bn_gamma,
    const float* __restrict__ bn_beta, const float* __restrict__ bn_mean,
    const float* __restrict__ bn_var, float* __restrict__ partial)
{
    __shared__ __align__(16) char smem[AROWS * ACOLS * 2];   // 46,400 B
    _Float16* s_a = (_Float16*)smem;
    float*    s_r = (float*)smem;    // reused: [8 wq][2 h][64 co][3 bin] = 12 KB

    const int bx = blockIdx.x;      // oh = 2*bx + h
    const int bt = blockIdx.y;
    const int b = bt / 90, t = bt % 90;
    const int tid = threadIdx.x;
    const int lane = tid & 63;
    const int wid = __builtin_amdgcn_readfirstlane(tid >> 6);

    // plane p (= c*3+kt) DMA: 11 rows x 464 B = 5104 B contiguous in global AND LDS.
    // waves 0..2 issue one 1024B chunk; wave 3 issues 1024B + 1008B tail (2 chunks).
    auto stage = [&](int p) {
        int c_ = p / 3, kt_ = p - c_ * 3;
        const char* gp = (const char*)(pim +
            ((size_t)((b * 92 + t + kt_) * 3 + c_) * 227 + 8 * bx) * ACOLS);
        char* lp = smem + p * 5104;
        if (wid < 3) {
            __builtin_amdgcn_global_load_lds((gu32*)(gp + wid * 1024 + lane * 16),
                                             (lu32*)(lp + wid * 1024), 16, 0, 0);
        } else {
            __builtin_amdgcn_global_load_lds((gu32*)(gp + 3072 + lane * 16),
                                             (lu32*)(lp + 3072), 16, 0, 0);
            if (lane < 63)
                __builtin_amdgcn_global_load_lds((gu32*)(gp + 4096 + lane * 16),
                                                 (lu32*)(lp + 4096), 16, 0, 0);
        }
    };

    // deep prologue: all 45 chunks in flight (waves 0-2: 9 each, wave 3: 18)
    stage(0); stage(1); stage(2); stage(3); stage(4);
    stage(5); stage(6); stage(7); stage(8);
    if (tid < 29) {                                   // zero row r=99 (kh=7 pad, x0 weight)
        half8 z = {};
        *(half8*)(s_a + 99 * ACOLS + tid * 8) = z;
    }
    asm volatile("s_waitcnt lgkmcnt(0)" ::: "memory");   // zero-row write drained

    const int wn = wid & 1, wm = wid >> 1;
    const int l15 = lane & 15, q = lane >> 4;

    f32x4 acc[2][2][2] = {};                 // [h][i(m-sub)][n(co-sub)]
    int owA = wm * 32 + l15;  if (owA > 55) owA = 55;
    int owB = owA + 16;       if (owB > 55) owB = 55;
    const int co0 = wn * 32 + l15;
    const int co1 = co0 + 16;
    const _Float16* baseA = s_a + q * ACOLS + 4 * owA;
    const _Float16* baseB = s_a + q * ACOLS + 4 * owB;
    const _Float16* bp0 = wBh + (size_t)q * 512 + co0 * 8;
    const _Float16* bp1 = bp0 + 128;                     // co1 = co0+16

// one K-step: row(kk,q) = 4kk + 3*(kk>>1) + q (q folded into bases); B at (4kk+q)*512
#define KK(kkc) do { \
    const int ro = (4 * (kkc) + 3 * ((kkc) >> 1)) * ACOLS; \
    half8 b0 = *(const half8*)(bp0 + (size_t)(kkc) * 2048); \
    half8 b1 = *(const half8*)(bp1 + (size_t)(kkc) * 2048); \
    half8 a00 = ld8(baseA + ro); \
    half8 a01 = ld8(baseB + ro); \
    half8 a10 = ld8(baseA + ro + 4 * ACOLS); \
    half8 a11 = ld8(baseB + ro + 4 * ACOLS); \
    acc[0][0][0] = __builtin_amdgcn_mfma_f32_16x16x32_f16(a00, b0, acc[0][0][0], 0, 0, 0); \
    acc[0][0][1] = __builtin_amdgcn_mfma_f32_16x16x32_f16(a00, b1, acc[0][0][1], 0, 0, 0); \
    acc[0][1][0] = __builtin_amdgcn_mfma_f32_16x16x32_f16(a01, b0, acc[0][1][0], 0, 0, 0); \
    acc[0][1][1] = __builtin_amdgcn_mfma_f32_16x16x32_f16(a01, b1, acc[0][1][1], 0, 0, 0); \
    acc[1][0][0] = __builtin_amdgcn_mfma_f32_16x16x32_f16(a10, b0, acc[1][0][0], 0, 0, 0); \
    acc[1][0][1] = __builtin_amdgcn_mfma_f32_16x16x32_f16(a10, b1, acc[1][0][1], 0, 0, 0); \
    acc[1][1][0] = __builtin_amdgcn_mfma_f32_16x16x32_f16(a11, b0, acc[1][1][0], 0, 0, 0); \
    acc[1][1][1] = __builtin_amdgcn_mfma_f32_16x16x32_f16(a11, b1, acc[1][1][1], 0, 0, 0); \
} while (0)

// counted wait: phase p needs planes <= p+1 landed. vmcnt retires in issue order, so
// waves 0-2 (1 chunk/plane, 9 outstanding): vmcnt(7-p); wave 3 (2/plane): vmcnt(14-2p).
#define WAITV(n1, n3) do { \
    if (wid == 3) asm volatile("s_waitcnt vmcnt(" #n3 ")" ::: "memory"); \
    else          asm volatile("s_waitcnt vmcnt(" #n1 ")" ::: "memory"); \
} while (0)

// phase p: own-wait planes <= p+1, barrier publishes across waves, compute kk=2p,2p+1
#define PHASE(p, W) do { \
    W; \
    __builtin_amdgcn_s_barrier(); \
    __builtin_amdgcn_s_setprio(1); \
    KK(2 * (p)); \
    KK(2 * (p) + 1); \
    __builtin_amdgcn_s_setprio(0); \
} while (0)

    PHASE(0, WAITV(7, 14));
    PHASE(1, WAITV(6, 12));
    PHASE(2, WAITV(5, 10));
    PHASE(3, WAITV(4, 8));
    PHASE(4, WAITV(3, 6));
    PHASE(5, WAITV(2, 4));
    PHASE(6, WAITV(1, 2));
    PHASE(7, WAITV(0, 0));
    PHASE(8, WAITV(0, 0));

#undef PHASE
#undef WAITV
#undef KK

    // BN/bias params loaded after the K-loop (kept out of the counted vmcnt window)
    float vg0 = bn_gamma[co0], vg1 = bn_gamma[co1];
    float vv0 = bn_var[co0],   vv1 = bn_var[co1];
    float vb0 = bn_beta[co0],  vb1 = bn_beta[co1];
    float vm0 = bn_mean[co0],  vm1 = bn_mean[co1];
    float vc0 = conv_b[co0],   vc1 = conv_b[co1];

    __syncthreads();   // done with s_a; reuse as s_r (full drain OK here)

    // ---- epilogue: bias+BN+exact GELU (fast erf), in-register 3-bin ow pooling ----
    float inv[2], sh[2], cb[2];
    inv[0] = vg0 / sqrtf(vv0 + 1e-5f);
    sh[0]  = vb0 - vm0 * inv[0];
    cb[0]  = vc0;
    inv[1] = vg1 / sqrtf(vv1 + 1e-5f);
    sh[1]  = vb1 - vm1 * inv[1];
    cb[1]  = vc1;
    #pragma unroll
    for (int h = 0; h < 2; ++h) {
        #pragma unroll
        for (int n = 0; n < 2; ++n) {
            float s0 = 0.f, s1 = 0.f, s2 = 0.f;
            #pragma unroll
            for (int i = 0; i < 2; ++i) {
                #pragma unroll
                for (int reg = 0; reg < 4; ++reg) {
                    int m = wm * 32 + i * 16 + q * 4 + reg;   // ow
                    float v = (acc[h][i][n][reg] + cb[n]) * inv[n] + sh[n];
                    float g = gelu_exact(v);
                    s0 += (m < 18) ? g : 0.f;
                    s1 += (m >= 18 && m < 37) ? g : 0.f;
                    s2 += (m >= 37 && m < 56) ? g : 0.f;
                }
            }
            int co = n ? co1 : co0;
            float* dst = s_r + (((wm * 4 + q) * 2 + h) * 64 + co) * 3;
            dst[0] = s0; dst[1] = s1; dst[2] = s2;
        }
    }
    __syncthreads();

    if (tid < 192) {    // 64 co x 3 bins; reduce 8 wq partials, both oh rows
        int co = tid / 3, j = tid % 3;
        #pragma unroll
        for (int hh = 0; hh < 2; ++hh) {
            float s = 0.f;
            #pragma unroll
            for (int wq = 0; wq < 8; ++wq)
                s += s_r[((wq * 2 + hh) * 64 + co) * 3 + j];
            partial[((size_t)(bt * 56 + 2 * bx + hh) * 64 + co) * 3 + j] = s;
        }
    }
}

// ---------------- Kernel 2: fused pool-over-oh + proj + in_proj -> xm_raw [bt][512] --------
__global__ __launch_bounds__(256) void ppi_kernel(
    const float* __restrict__ partial, const float* __restrict__ proj_w,
    const float* __restrict__ proj_b, const float* __restrict__ m_in_w,
    float* __restrict__ xm_raw)
{
    __shared__ __align__(16) float s_part[10752];   // [oh 56][co 64][3]
    __shared__ __align__(16) float s_pool[576];
    __shared__ __align__(16) float s_xp[128];
    int bt = blockIdx.x, tid = threadIdx.x;

    const f32x4* src4 = (const f32x4*)(partial + (size_t)bt * 10752);
    f32x4* dst4 = (f32x4*)s_part;
    for (int i = tid; i < 2688; i += 256) dst4[i] = src4[i];
    __syncthreads();

    for (int f = tid; f < 576; f += 256) {
        int co = f / 9, r = f % 9, i = r / 3, j = r % 3;
        const int sh[3] = {0, 18, 37}, eh[3] = {18, 37, 56};
        const float cnt[3] = {18.f, 19.f, 19.f};
        float s = 0.f;
        for (int oh = sh[i]; oh < eh[i]; ++oh)
            s += s_part[oh * 192 + co * 3 + j];
        s_pool[f] = s / (cnt[i] * cnt[j]);
    }
    __syncthreads();
    if (tid < 128) {
        const f32x4* w = (const f32x4*)(proj_w + (size_t)tid * 576);
        const f32x4* x4 = (const f32x4*)s_pool;
        f32x4 a = {};
        #pragma unroll 4
        for (int f = 0; f < 144; ++f) a += w[f] * x4[f];
        s_xp[tid] = proj_b[tid] + a.x + a.y + a.z + a.w;
    }
    __syncthreads();
    for (int o = tid; o < 512; o += 256) {
        const f32x4* w = (const f32x4*)(m_in_w + (size_t)o * 128);
        const f32x4* x4 = (const f32x4*)s_xp;
        f32x4 a = {};
        #pragma unroll 4
        for (int f = 0; f < 32; ++f) a += w[f] * x4[f];
        xm_raw[(size_t)bt * 512 + o] = a.x + a.y + a.z + a.w;
    }
}

// ---------------- Kernel 3: fused dwconv+silu -> xc, xdbl, delta ----------------
__global__ __launch_bounds__(256) void dxd_kernel(
    const float* __restrict__ xm_raw, const float* __restrict__ m_conv_w,
    const float* __restrict__ m_conv_b, const float* __restrict__ m_x_w,
    const float* __restrict__ m_dt_w, const float* __restrict__ m_dt_b,
    float* __restrict__ xc, float* __restrict__ xdbl, float* __restrict__ delta)
{
    __shared__ __align__(16) float s_xc[256];
    __shared__ float s_xd[40];
    int bt = blockIdx.x, d = threadIdx.x;
    int b = bt / 90, l = bt % 90;
    float s = m_conv_b[d];
    #pragma unroll
    for (int k = 0; k < 4; ++k) {
        int lk = l - 3 + k;
        if (lk >= 0) s += xm_raw[(size_t)(b * 90 + lk) * 512 + d] * m_conv_w[d * 4 + k];
    }
    float xcv = s / (1.f + expf(-s));
    s_xc[d] = xcv;
    xc[(size_t)bt * 256 + d] = xcv;
    __syncthreads();
    if (d < 40) {
        const f32x4* w = (const f32x4*)(m_x_w + (size_t)d * 256);
        const f32x4* x4 = (const f32x4*)s_xc;
        f32x4 a = {};
        #pragma unroll 4
        for (int f = 0; f < 64; ++f) a += w[f] * x4[f];
        float v = a.x + a.y + a.z + a.w;
        s_xd[d] = v;
        xdbl[(size_t)bt * 40 + d] = v;
    }
    __syncthreads();
    float t2 = m_dt_b[d];
    #pragma unroll
    for (int r = 0; r < 8; ++r) t2 += s_xd[r] * m_dt_w[d * 8 + r];
    delta[(size_t)bt * 256 + d] = (t2 > 20.f) ? t2 : log1pf(expf(t2));
}

// ---------------- Kernel 4: selective scan (8 blocks x 128 thr) ----------------
__global__ __launch_bounds__(128) void scan_kernel(
    const float* __restrict__ xc, const float* __restrict__ xdbl,
    const float* __restrict__ delta, const float* __restrict__ m_A_log,
    const float* __restrict__ m_D, const float* __restrict__ xm_raw,
    float* __restrict__ y)
{
    int b = blockIdx.x >> 1;
    int d = (blockIdx.x & 1) * 128 + threadIdx.x;
    float A[16], h[16];
    #pragma unroll
    for (int n = 0; n < 16; ++n) { A[n] = -expf(m_A_log[d * 16 + n]); h[n] = 0.f; }
    float Dd = m_D[d];
    size_t base = (size_t)b * 90;
    float dl = delta[base * 256 + d];
    float x  = xc[base * 256 + d];
    float r  = xm_raw[base * 512 + 256 + d];
    for (int l = 0; l < 90; ++l) {
        size_t bt = base + l;
        float dln = 0.f, xn = 0.f, rn = 0.f;
        if (l < 89) {
            dln = delta[(bt + 1) * 256 + d];
            xn  = xc[(bt + 1) * 256 + d];
            rn  = xm_raw[(bt + 1) * 512 + 256 + d];
        }
        const float* Bc = xdbl + bt * 40 + 8;
        float yl = 0.f;
        #pragma unroll
        for (int n = 0; n < 16; ++n) {
            float dA = expf(dl * A[n]);
            h[n] = dA * h[n] + dl * Bc[n] * x;
            yl += h[n] * Bc[16 + n];
        }
        yl += x * Dd;
        float sr = r / (1.f + expf(-r));
        y[bt * 256 + d] = yl * sr;
        dl = dln; x = xn; r = rn;
    }
}

// ---------------- Kernel 5: y @ out_w.T -> out [bt][128] ----------------
__global__ __launch_bounds__(128) void outproj_kernel(
    const float* __restrict__ y, const float* __restrict__ m_out_w,
    float* __restrict__ out)
{
    __shared__ __align__(16) float s_y[256];
    int bt = blockIdx.x, tid = threadIdx.x;
    for (int i = tid; i < 256; i += 128) s_y[i] = y[(size_t)bt * 256 + i];
    __syncthreads();
    const f32x4* w = (const f32x4*)(m_out_w + (size_t)tid * 256);
    const f32x4* x4 = (const f32x4*)s_y;
    f32x4 a = {};
    #pragma unroll 4
    for (int f = 0; f < 64; ++f) a += w[f] * x4[f];
    out[(size_t)bt * 128 + tid] = a.x + a.y + a.z + a.w;
}

extern "C" void kernel_launch(void* const* d_in, const int* in_sizes, int n_in,
                              void* d_out, int out_size, void* d_ws, size_t ws_size,
                              hipStream_t stream) {
    const float* rgb      = (const float*)d_in[0];
    const float* conv_w   = (const float*)d_in[1];
    const float* conv_b   = (const float*)d_in[2];
    const float* bn_gamma = (const float*)d_in[3];
    const float* bn_beta  = (const float*)d_in[4];
    const float* bn_mean  = (const float*)d_in[5];
    const float* bn_var   = (const float*)d_in[6];
    const float* proj_w   = (const float*)d_in[7];
    const float* proj_b   = (const float*)d_in[8];
    const float* m_in_w   = (const float*)d_in[9];
    const float* m_conv_w = (const float*)d_in[10];
    const float* m_conv_b = (const float*)d_in[11];
    const float* m_x_w    = (const float*)d_in[12];
    const float* m_dt_w   = (const float*)d_in[13];
    const float* m_dt_b   = (const float*)d_in[14];
    const float* m_A_log  = (const float*)d_in[15];
    const float* m_D      = (const float*)d_in[16];
    const float* m_out_w  = (const float*)d_in[17];
    float* out = (float*)d_out;

    float* ws      = (float*)d_ws;
    float* partial = ws;                  // 3,870,720 floats
    float* xm_raw  = partial + 3870720;   // 184,320
    float* xc      = xm_raw + 184320;     // 92,160
    float* xdbl    = xc + 92160;          // 14,400
    float* delta   = xdbl + 14400;        // 92,160
    float* yb      = delta + 92160;       // 92,160
    _Float16* wBh  = (_Float16*)(yb + 92160);      // 36,864 halfs
    _Float16* pim  = (_Float16*)(yb + 92160 + 18432);  // 58,132,416 halfs (~116 MB)

    pad_kernel<<<28390, 256, 0, stream>>>(rgb, pim);
    wprep_kernel<<<144, 256, 0, stream>>>(conv_w, wBh);
    conv_mfma_kernel<<<dim3(28, 360), 256, 0, stream>>>(pim, wBh, conv_b, bn_gamma,
                                                        bn_beta, bn_mean, bn_var, partial);
    ppi_kernel<<<360, 256, 0, stream>>>(partial, proj_w, proj_b, m_in_w, xm_raw);
    dxd_kernel<<<360, 256, 0, stream>>>(xm_raw, m_conv_w, m_conv_b, m_x_w,
                                        m_dt_w, m_dt_b, xc, xdbl, delta);
    scan_kernel<<<8, 128, 0, stream>>>(xc, xdbl, delta, m_A_log, m_D, xm_raw, yb);
    outproj_kernel<<<360, 128, 0, stream>>>(yb, m_out_w, out);
}